// Round 10
// baseline (370.603 us; speedup 1.0000x reference)
//
#include <hip/hip_runtime.h>
#include <cstdint>
#include <cstddef>

// Problem constants: b=2,s=32 -> BS=64; c=128; h=w=24 -> L=576
constexpr int BS   = 64;
constexpr int Cc   = 128;
constexpr int Lc   = 576;
constexpr int VD   = 128;   // v dim per head
constexpr int HID  = 256;
constexpr int OUTC = 128;
constexpr int NPIX = BS * Lc;  // 36864

typedef __bf16 bf16x8 __attribute__((ext_vector_type(8)));
typedef float  f32x4  __attribute__((ext_vector_type(4)));
typedef unsigned short u16x8 __attribute__((ext_vector_type(8)));
typedef unsigned int   u32x4 __attribute__((ext_vector_type(4)));

__device__ __forceinline__ unsigned short f2bf(float f) {
  unsigned int u = __builtin_bit_cast(unsigned int, f);
  u += 0x7fffu + ((u >> 16) & 1u);   // RTNE (inputs finite)
  return (unsigned short)(u >> 16);
}
__device__ __forceinline__ float bf2f(unsigned short h) {
  unsigned int u = ((unsigned int)h) << 16;
  return __builtin_bit_cast(float, u);
}
// pack value as hi-bf16 (bits 31:16) | lo-bf16 (bits 15:0), lo = residual
__device__ __forceinline__ unsigned int packhl(float v) {
  unsigned short hi = f2bf(v);
  unsigned short lo = f2bf(v - bf2f(hi));
  return ((unsigned int)hi << 16) | (unsigned int)lo;
}
// unpack 8 packed elements (two 16B u32x4 loads) -> hi/lo bf16x8 fragments
__device__ __forceinline__ void unpack8(u32x4 a, u32x4 b, bf16x8& hi, bf16x8& lo) {
  u32x4 h, l;
  h[0] = (a[1] & 0xffff0000u) | (a[0] >> 16);
  l[0] = (a[1] << 16)         | (a[0] & 0xffffu);
  h[1] = (a[3] & 0xffff0000u) | (a[2] >> 16);
  l[1] = (a[3] << 16)         | (a[2] & 0xffffu);
  h[2] = (b[1] & 0xffff0000u) | (b[0] >> 16);
  l[2] = (b[1] << 16)         | (b[0] & 0xffffu);
  h[3] = (b[3] & 0xffff0000u) | (b[2] >> 16);
  l[3] = (b[3] << 16)         | (b[2] & 0xffffu);
  hi = __builtin_bit_cast(bf16x8, h);
  lo = __builtin_bit_cast(bf16x8, l);
}

#define MFMA16(a, b, c) __builtin_amdgcn_mfma_f32_16x16x32_bf16((a), (b), (c), 0, 0, 0)

// ---------------------------------------------------------------------------
// Kernel 1: CPB LUT, 2 heads x 47 x 47.
// ---------------------------------------------------------------------------
__global__ __launch_bounds__(256) void cpb_kernel(const float* __restrict__ w1,
                                                  const float* __restrict__ b1,
                                                  const float* __restrict__ w2,
                                                  float* __restrict__ tab) {
  int idx = blockIdx.x * 256 + threadIdx.x;
  if (idx >= 47 * 47) return;
  int dy = idx / 47 - 23, dx = idx % 47 - 23;
  float fy = (float)dy * (8.0f / 23.0f);
  float fx = (float)dx * (8.0f / 23.0f);
  fy = copysignf(log2f(1.0f + fabsf(fy)) * (1.0f / 3.0f), fy);
  fx = copysignf(log2f(1.0f + fabsf(fx)) * (1.0f / 3.0f), fx);
  float a0 = 0.f, a1 = 0.f;
  for (int hh = 0; hh < 128; hh++) {
    float hv = fmaxf(w1[2 * hh] * fy + w1[2 * hh + 1] * fx + b1[hh], 0.f);
    a0 += w2[hh] * hv;
    a1 += w2[128 + hh] * hv;
  }
  tab[idx] = a0;
  tab[2209 + idx] = a1;
}

// ---------------------------------------------------------------------------
// Kernel 1b: bias swizzled for the block-cooperative attention (r7 layout):
// biasC[hh][mtile(36)][wave(4)][g(5)][lane(64)][8] bf16.
// ---------------------------------------------------------------------------
__global__ __launch_bounds__(256) void bias_mat(const float* __restrict__ tab,
                                                unsigned short* __restrict__ biasC) {
  int id = blockIdx.x * 256 + threadIdx.x;
  if (id >= 737280) return;
  int id2 = id % 2560;
  int grp = id / 2560;            // ((hh*36+mt)*4+wave)
  int wave = grp & 3;
  int mt = (grp >> 2) % 36;
  int hh = grp / 144;
  int g = id2 / 512;
  int lane = (id2 >> 3) & 63;
  int k = id2 & 7;
  int e = g * 8 + k;
  unsigned short val = 0;
  if (e < 36) {
    int ln = e >> 2, r = e & 3;
    int nt = wave * 9 + ln;
    int i = mt * 16 + (lane >> 4) * 4 + r;
    int j = nt * 16 + (lane & 15);
    int yi = i / 24, xi = i - yi * 24;
    int yj = j / 24, xj = j - yj * 24;
    val = f2bf(tab[hh * 2209 + (yi - yj + 23) * 47 + (xi - xj + 23)]);
  }
  biasC[id] = val;
}

// ---------------------------------------------------------------------------
// Kernel 1c: split all GEMM weights into bf16 hi/lo (row-major [n][k] kept).
// ---------------------------------------------------------------------------
__global__ __launch_bounds__(256) void prep_w(
    const float* __restrict__ w1, const float* __restrict__ w2,
    const float* __restrict__ qkw, const float* __restrict__ vw,
    unsigned short* __restrict__ w1h, unsigned short* __restrict__ w1l,
    unsigned short* __restrict__ w2h, unsigned short* __restrict__ w2l,
    unsigned short* __restrict__ wqkh, unsigned short* __restrict__ wqkl,
    unsigned short* __restrict__ wvh, unsigned short* __restrict__ wvl) {
  int id = blockIdx.x * 256 + threadIdx.x;
  const float* src;
  unsigned short *dh, *dl;
  int off;
  if (id < 65536)       { src = w1;  dh = w1h;  dl = w1l;  off = id; }
  else if (id < 98304)  { src = w2;  dh = w2h;  dl = w2l;  off = id - 65536; }
  else if (id < 131072) { src = qkw; dh = wqkh; dl = wqkl; off = id - 98304; }
  else if (id < 163840) { src = vw;  dh = wvh;  dl = wvl;  off = id - 131072; }
  else return;
  float v = src[off];
  unsigned short hi = f2bf(v);
  dh[off] = hi;
  dl[off] = f2bf(v - bf2f(hi));
}

// ---------------------------------------------------------------------------
// Kernel 1d: transpose+split x[bs][c][l] -> xph/xpl pixel-major [p][128] bf16.
// ---------------------------------------------------------------------------
__global__ __launch_bounds__(256) void prep_x(const float* __restrict__ x,
                                              unsigned short* __restrict__ xph,
                                              unsigned short* __restrict__ xpl) {
  __shared__ float xt[128 * 65];
  const int l0 = blockIdx.x * 64, bs = blockIdx.y;
  const int t = threadIdx.x;
  const float* xb = x + (size_t)bs * Cc * Lc;
#pragma unroll
  for (int pass = 0; pass < 8; pass++) {
    int f = pass * 1024 + t * 4;
    int c = f >> 6, ll = f & 63;
    *(float4*)(xt + c * 65 + ll) = *(const float4*)(xb + c * Lc + l0 + ll);
  }
  __syncthreads();
  const int rowl = t >> 2, c0 = (t & 3) * 32;
  const size_t p = (size_t)bs * Lc + l0 + rowl;
  unsigned short hbuf[32], lbuf[32];
#pragma unroll
  for (int i = 0; i < 32; i++) {
    float v = xt[(c0 + i) * 65 + rowl];
    unsigned short hi = f2bf(v);
    hbuf[i] = hi;
    lbuf[i] = f2bf(v - bf2f(hi));
  }
#pragma unroll
  for (int g = 0; g < 4; g++) {
    *(u16x8*)(xph + p * 128 + c0 + g * 8) = *(u16x8*)(hbuf + g * 8);
    *(u16x8*)(xpl + p * 128 + c0 + g * 8) = *(u16x8*)(lbuf + g * 8);
  }
}

// ---------------------------------------------------------------------------
// Kernel 2: QKV via MFMA, split-3 bf16 (unchanged, passing).
// ---------------------------------------------------------------------------
__global__ __launch_bounds__(256, 2) void qkv_mfma(
    const unsigned short* __restrict__ xh, const unsigned short* __restrict__ xl,
    const unsigned short* __restrict__ wqkh, const unsigned short* __restrict__ wqkl,
    const unsigned short* __restrict__ wvh, const unsigned short* __restrict__ wvl,
    unsigned short* __restrict__ qg, unsigned short* __restrict__ kg,
    unsigned short* __restrict__ vg) {
  __shared__ unsigned short vt[128 * 130];
  const int t = threadIdx.x;
  const int wv = t >> 6, lane = t & 63;
  const int quad = lane >> 4, cc = lane & 15;
  const int by = blockIdx.y;
  const int m0 = blockIdx.x * 128 + (wv & 1) * 64;
  const int n0 = (wv >> 1) * 64;
  const unsigned short* Wh = (by < 2) ? wqkh : wvh;
  const unsigned short* Wl = (by < 2) ? wqkl : wvl;
  const int wrow0 = (by & 1) * 128 + n0;
  f32x4 acc[4][4];
#pragma unroll
  for (int i = 0; i < 4; i++)
#pragma unroll
    for (int j = 0; j < 4; j++) acc[i][j] = (f32x4){0.f, 0.f, 0.f, 0.f};
  for (int kc = 0; kc < 4; kc++) {
    const int kb = kc * 32 + quad * 8;
    bf16x8 Ah[4], Al[4], Bh[4], Bl[4];
#pragma unroll
    for (int i = 0; i < 4; i++) {
      size_t ar = (size_t)(m0 + i * 16 + cc) * 128 + kb;
      Ah[i] = *(const bf16x8*)(xh + ar);
      Al[i] = *(const bf16x8*)(xl + ar);
      size_t br = (size_t)(wrow0 + i * 16 + cc) * 128 + kb;
      Bh[i] = *(const bf16x8*)(Wh + br);
      Bl[i] = *(const bf16x8*)(Wl + br);
    }
#pragma unroll
    for (int i = 0; i < 4; i++)
#pragma unroll
      for (int j = 0; j < 4; j++) {
        acc[i][j] = MFMA16(Ah[i], Bh[j], acc[i][j]);
        acc[i][j] = MFMA16(Al[i], Bh[j], acc[i][j]);
        acc[i][j] = MFMA16(Ah[i], Bl[j], acc[i][j]);
      }
  }
  if (by < 2) {
    const float sc = (by == 0) ? 0.125f : 1.0f;
#pragma unroll
    for (int j = 0; j < 4; j++) {
      int o = n0 + j * 16 + cc;
#pragma unroll
      for (int i = 0; i < 4; i++)
#pragma unroll
        for (int r = 0; r < 4; r++) {
          int pl = (wv & 1) * 64 + i * 16 + quad * 4 + r;
          vt[pl * 130 + o] = f2bf(acc[i][j][r] * sc);
        }
    }
    __syncthreads();
    unsigned short* dst = (by == 0) ? qg : kg;
    const int pl = t >> 1, head = t & 1;
    const int p = blockIdx.x * 128 + pl;
    const int bs = p / 576, l = p - bs * 576;
    unsigned short* drow = dst + ((size_t)(bs * 2 + head) * Lc + l) * 64;
#pragma unroll
    for (int g = 0; g < 8; g++)
      *(u16x8*)(drow + g * 8) = *(const u16x8*)(vt + pl * 130 + head * 64 + g * 8);
  } else {
    const int head = by - 2;
#pragma unroll
    for (int j = 0; j < 4; j++) {
      int d = n0 + j * 16 + cc;
#pragma unroll
      for (int i = 0; i < 4; i++)
#pragma unroll
        for (int r = 0; r < 4; r++) {
          int pl = (wv & 1) * 64 + i * 16 + quad * 4 + r;
          vt[d * 130 + pl] = f2bf(acc[i][j][r]);
        }
    }
    __syncthreads();
    const int d = t >> 1, half = (t & 1) * 64;
#pragma unroll
    for (int c8 = 0; c8 < 8; c8++) {
      int pl = half + c8 * 8;
      int p = blockIdx.x * 128 + pl;
      int bs = p / 576, l = p - bs * 576;
      *(u16x8*)(vg + ((size_t)(bs * 2 + head) * VD + d) * Lc + l) =
          *(u16x8*)(vt + d * 130 + pl);
    }
  }
}

// ---------------------------------------------------------------------------
// Kernel 3: MFMA attention — EXACT r8 version (126 us, passing). r9's
// pipelined variant (256,3 + pre-barrier V prefetch) core-dumped; reverted
// per rigor rule (crash without explanation doesn't get re-rolled).
// ---------------------------------------------------------------------------
__global__ __launch_bounds__(256, 4) void attn_kernel(
    const unsigned short* __restrict__ qg,
    const unsigned short* __restrict__ kg,
    const unsigned short* __restrict__ vg,
    const unsigned short* __restrict__ biasC,
    const float* __restrict__ sa_bias,
    unsigned int* __restrict__ aout_p) {
  constexpr int PP = 580;  // row pitch (u16): measured 0 bank conflicts (r6-r8)
  __shared__ unsigned short Pb[16 * PP];          // 18,560 B
  __shared__ float psum[4][16];
  const int pair = blockIdx.x;   // bs*2+hh fastest -> pair%8 pins to one XCD
  const int hh = pair & 1, bs = pair >> 1;
  const int mtile = blockIdx.y;
  const int m0 = mtile * 16;
  const int t = threadIdx.x;
  const int wv = t >> 6, lane = t & 63;
  const int quad = lane >> 4, c = lane & 15;
  const unsigned short* qb = qg + ((size_t)pair * Lc + m0) * 64;
  const unsigned short* kb = kg + (size_t)pair * Lc * 64;
  const unsigned short* vb = vg + (size_t)pair * VD * Lc;
  const bf16x8 qa0 = *(const bf16x8*)(qb + c * 64 + quad * 8);
  const bf16x8 qa1 = *(const bf16x8*)(qb + c * 64 + 32 + quad * 8);
  // ---- S init = bias (5 coalesced 16B loads/lane) ----
  const unsigned short* bbase =
      biasC + ((((size_t)hh * 36 + mtile) * 4 + wv) * 5) * 512;
  f32x4 S[9];
#pragma unroll
  for (int g = 0; g < 5; g++) {
    u16x8 bv = *(const u16x8*)(bbase + g * 512 + lane * 8);
#pragma unroll
    for (int k = 0; k < 8; k++) {
      int e = g * 8 + k;
      if (e < 36) S[e >> 2][e & 3] = bf2f(bv[k]);
    }
  }
  // ---- QK: this wave's 9 col-tiles (18 MFMAs) ----
#pragma unroll
  for (int ln = 0; ln < 9; ln++) {
    int nt = wv * 9 + ln;
    const unsigned short* kp = kb + (size_t)(nt * 16 + c) * 64 + quad * 8;
    bf16x8 b0 = *(const bf16x8*)kp;
    bf16x8 b1 = *(const bf16x8*)(kp + 32);
    S[ln] = MFMA16(qa1, b1, MFMA16(qa0, b0, S[ln]));
  }
  // ---- exp (no max; scores O(+-10), fp32 exp safe) + partial sums + P ----
  float sm[4] = {0.f, 0.f, 0.f, 0.f};
#pragma unroll
  for (int ln = 0; ln < 9; ln++)
#pragma unroll
    for (int r = 0; r < 4; r++) {
      float e = __expf(S[ln][r]);
      sm[r] += e;
      Pb[(quad * 4 + r) * PP + (wv * 9 + ln) * 16 + c] = f2bf(e);
    }
#pragma unroll
  for (int sh = 1; sh < 16; sh <<= 1)
#pragma unroll
    for (int r = 0; r < 4; r++) sm[r] += __shfl_xor(sm[r], sh);
  if (c == 0)
#pragma unroll
    for (int r = 0; r < 4; r++) psum[wv][quad * 4 + r] = sm[r];
  __syncthreads();
  float inv[4];
#pragma unroll
  for (int r = 0; r < 4; r++) {
    int row = quad * 4 + r;
    inv[r] = 1.0f / (psum[0][row] + psum[1][row] + psum[2][row] + psum[3][row]);
  }
  // ---- PV: this wave's 2 d-chunks over all 576 cols (36 MFMAs) ----
  const int nd0 = wv * 2;
  f32x4 O[2] = {(f32x4){0.f, 0.f, 0.f, 0.f}, (f32x4){0.f, 0.f, 0.f, 0.f}};
#pragma unroll
  for (int kc = 0; kc < 18; kc++) {
    bf16x8 pa = *(const bf16x8*)(Pb + c * PP + kc * 32 + quad * 8);
#pragma unroll
    for (int dd = 0; dd < 2; dd++) {
      bf16x8 vf = *(const bf16x8*)(vb + (size_t)((nd0 + dd) * 16 + c) * Lc +
                                   kc * 32 + quad * 8);
      O[dd] = MFMA16(pa, vf, O[dd]);
    }
  }
  // ---- epilogue: O/sum + sa_bias -> aout packed u32 [p][256] ----
  unsigned int* obp = aout_p + ((size_t)bs * Lc + m0) * HID + hh * 128;
#pragma unroll
  for (int dd = 0; dd < 2; dd++) {
    float sb = sa_bias[hh * 128 + (nd0 + dd) * 16 + c];
#pragma unroll
    for (int r = 0; r < 4; r++) {
      float v = O[dd][r] * inv[r] + sb;
      obp[(size_t)(quad * 4 + r) * HID + (nd0 + dd) * 16 + c] = packhl(v);
    }
  }
}

// ---------------------------------------------------------------------------
// Kernel 4: MLP layer 1 via MFMA — retiled 64x128 (was 128x128). acc[4][2]
// (32 VGPR) + 12 frags (48) fits the (256,2) 128-VGPR cap with room for
// in-flight loads (old acc[4][4]+16 frags = 128+ forced load serialization).
// Grid (576,2) = 1152 blocks (was 576).
// ---------------------------------------------------------------------------
__global__ __launch_bounds__(256, 2) void mlp1_mfma(
    const unsigned int* __restrict__ ap,
    const unsigned short* __restrict__ w1h, const unsigned short* __restrict__ w1l,
    const float* __restrict__ b1,
    unsigned int* __restrict__ y1p) {
  const int t = threadIdx.x;
  const int wv = t >> 6, lane = t & 63;
  const int quad = lane >> 4, cc = lane & 15;
  const int m0 = blockIdx.x * 64;
  const int n0 = blockIdx.y * 128 + wv * 32;
  f32x4 acc[4][2];
#pragma unroll
  for (int i = 0; i < 4; i++)
#pragma unroll
    for (int j = 0; j < 2; j++) acc[i][j] = (f32x4){0.f, 0.f, 0.f, 0.f};
  for (int kc = 0; kc < 8; kc++) {
    const int kb = kc * 32 + quad * 8;
    bf16x8 Ah[4], Al[4], Bh[2], Bl[2];
#pragma unroll
    for (int i = 0; i < 4; i++) {
      const unsigned int* arow = ap + (size_t)(m0 + i * 16 + cc) * HID + kb;
      u32x4 pa = *(const u32x4*)arow;
      u32x4 pb = *(const u32x4*)(arow + 4);
      unpack8(pa, pb, Ah[i], Al[i]);
    }
#pragma unroll
    for (int j = 0; j < 2; j++) {
      size_t br = (size_t)(n0 + j * 16 + cc) * HID + kb;
      Bh[j] = *(const bf16x8*)(w1h + br);
      Bl[j] = *(const bf16x8*)(w1l + br);
    }
#pragma unroll
    for (int i = 0; i < 4; i++)
#pragma unroll
      for (int j = 0; j < 2; j++) {
        acc[i][j] = MFMA16(Ah[i], Bh[j], acc[i][j]);
        acc[i][j] = MFMA16(Al[i], Bh[j], acc[i][j]);
        acc[i][j] = MFMA16(Ah[i], Bl[j], acc[i][j]);
      }
  }
#pragma unroll
  for (int j = 0; j < 2; j++) {
    int col = n0 + j * 16 + cc;
    float bias = b1[col];
#pragma unroll
    for (int i = 0; i < 4; i++) {
#pragma unroll
      for (int r = 0; r < 4; r++) {
        int row = m0 + i * 16 + quad * 4 + r;
        float v = acc[i][j][r] + bias;
        float g = 0.5f * v * (1.0f + erff(v * 0.70710678118654752f));
        y1p[(size_t)row * HID + col] = packhl(g);
      }
    }
  }
}

// ---------------------------------------------------------------------------
// Kernel 5: MLP layer 2 via MFMA — retiled 64x128, grid 576 blocks (was 288:
// only ~1.1 blocks/CU -> 25% occupancy ceiling from grid size alone).
// ---------------------------------------------------------------------------
__global__ __launch_bounds__(256, 2) void mlp2_mfma(
    const unsigned int* __restrict__ yp,
    const unsigned short* __restrict__ w2h, const unsigned short* __restrict__ w2l,
    const float* __restrict__ b2, float* __restrict__ out) {
  const int t = threadIdx.x;
  const int wv = t >> 6, lane = t & 63;
  const int quad = lane >> 4, cc = lane & 15;
  const int m0 = blockIdx.x * 64;
  const int n0 = wv * 32;
  f32x4 acc[4][2];
#pragma unroll
  for (int i = 0; i < 4; i++)
#pragma unroll
    for (int j = 0; j < 2; j++) acc[i][j] = (f32x4){0.f, 0.f, 0.f, 0.f};
  for (int kc = 0; kc < 8; kc++) {
    const int kb = kc * 32 + quad * 8;
    bf16x8 Ah[4], Al[4], Bh[2], Bl[2];
#pragma unroll
    for (int i = 0; i < 4; i++) {
      const unsigned int* arow = yp + (size_t)(m0 + i * 16 + cc) * HID + kb;
      u32x4 pa = *(const u32x4*)arow;
      u32x4 pb = *(const u32x4*)(arow + 4);
      unpack8(pa, pb, Ah[i], Al[i]);
    }
#pragma unroll
    for (int j = 0; j < 2; j++) {
      size_t br = (size_t)(n0 + j * 16 + cc) * HID + kb;
      Bh[j] = *(const bf16x8*)(w2h + br);
      Bl[j] = *(const bf16x8*)(w2l + br);
    }
#pragma unroll
    for (int i = 0; i < 4; i++)
#pragma unroll
      for (int j = 0; j < 2; j++) {
        acc[i][j] = MFMA16(Ah[i], Bh[j], acc[i][j]);
        acc[i][j] = MFMA16(Al[i], Bh[j], acc[i][j]);
        acc[i][j] = MFMA16(Ah[i], Bl[j], acc[i][j]);
      }
  }
#pragma unroll
  for (int i = 0; i < 4; i++) {
    int p = m0 + i * 16 + quad * 4;          // 4 consecutive pixels
    int bs = p / Lc, l = p - bs * Lc;        // never straddles (4 | 576)
#pragma unroll
    for (int j = 0; j < 2; j++) {
      int col = n0 + j * 16 + cc;
      float bias = b2[col];
      float4 v = make_float4(acc[i][j][0] + bias, acc[i][j][1] + bias,
                             acc[i][j][2] + bias, acc[i][j][3] + bias);
      *(float4*)(out + ((size_t)bs * OUTC + col) * Lc + l) = v;
    }
  }
}

// ---------------------------------------------------------------------------
// ws layout (bytes; sizes verified in BYTES):
//   tab    @ 0            (17,672)
//   biasC  @ 65,536       (1,474,560)  ends  1,540,096
//   qg     @ 1,572,864    (9,437,184)  ends 11,010,048
//   kg     @ 11,010,048   (9,437,184)  ends 20,447,232
//   vg     @ 20,447,232   (18,874,368) ends 39,321,600
//   xph    @ 39,321,600   (9,437,184)  ends 48,758,784
//   xpl    @ 48,758,784   (9,437,184)  ends 58,195,968
//   aout_p @ 58,195,968   (37,748,736) ends 95,944,704
//   y1p    = alias @ 1,572,864 (37,748,736 = q+k+v region, dead after attn)
//   w1h @ 95,944,704  w1l @ 96,075,776  (131,072 each)
//   w2h @ 96,206,848  w2l @ 96,272,384  (65,536 each)
//   wqkh @ 96,337,920 wqkl @ 96,403,456 (65,536 each)
//   wvh @ 96,468,992  wvl @ 96,534,528  (65,536 each)  total 96,600,064 B
// ---------------------------------------------------------------------------
extern "C" void kernel_launch(void* const* d_in, const int* in_sizes, int n_in,
                              void* d_out, int out_size, void* d_ws, size_t ws_size,
                              hipStream_t stream) {
  const float* x    = (const float*)d_in[0];
  const float* qk_w = (const float*)d_in[1];
  const float* v_w  = (const float*)d_in[2];
  const float* cw1  = (const float*)d_in[3];
  const float* cb1  = (const float*)d_in[4];
  const float* cw2  = (const float*)d_in[5];
  const float* sab  = (const float*)d_in[6];
  const float* mw1  = (const float*)d_in[7];
  const float* mb1  = (const float*)d_in[8];
  const float* mw2  = (const float*)d_in[9];
  const float* mb2  = (const float*)d_in[10];
  float* out = (float*)d_out;
  char* ws = (char*)d_ws;

  float* tab = (float*)(ws);
  unsigned short* biasC  = (unsigned short*)(ws + 65536);
  unsigned short* qg     = (unsigned short*)(ws + 1572864);
  unsigned short* kg     = (unsigned short*)(ws + 11010048);
  unsigned short* vg     = (unsigned short*)(ws + 20447232);
  unsigned short* xph    = (unsigned short*)(ws + 39321600);
  unsigned short* xpl    = (unsigned short*)(ws + 48758784);
  unsigned int*   aout_p = (unsigned int*)(ws + 58195968);
  unsigned int*   y1p    = (unsigned int*)(ws + 1572864);   // alias q/k/v
  unsigned short* w1h    = (unsigned short*)(ws + 95944704);
  unsigned short* w1l    = (unsigned short*)(ws + 96075776);
  unsigned short* w2h    = (unsigned short*)(ws + 96206848);
  unsigned short* w2l    = (unsigned short*)(ws + 96272384);
  unsigned short* wqkh   = (unsigned short*)(ws + 96337920);
  unsigned short* wqkl   = (unsigned short*)(ws + 96403456);
  unsigned short* wvh    = (unsigned short*)(ws + 96468992);
  unsigned short* wvl    = (unsigned short*)(ws + 96534528);

  cpb_kernel<<<dim3(9), dim3(256), 0, stream>>>(cw1, cb1, cw2, tab);
  bias_mat<<<dim3(2880), dim3(256), 0, stream>>>(tab, biasC);
  prep_w<<<dim3(640), dim3(256), 0, stream>>>(mw1, mw2, qk_w, v_w,
                                              w1h, w1l, w2h, w2l,
                                              wqkh, wqkl, wvh, wvl);
  prep_x<<<dim3(9, 64), dim3(256), 0, stream>>>(x, xph, xpl);
  qkv_mfma<<<dim3(288, 4), dim3(256), 0, stream>>>(xph, xpl, wqkh, wqkl,
                                                   wvh, wvl, qg, kg, vg);
  attn_kernel<<<dim3(128, 36), dim3(256), 0, stream>>>(qg, kg, vg, biasC, sab,
                                                       aout_p);
  mlp1_mfma<<<dim3(576, 2), dim3(256), 0, stream>>>(aout_p, w1h, w1l, mb1, y1p);
  mlp2_mfma<<<dim3(576), dim3(256), 0, stream>>>(y1p, w2h, w2l, mb2, out);
}